// Round 1
// baseline (2052.948 us; speedup 1.0000x reference)
//
#include <hip/hip_runtime.h>
#include <hip/hip_bf16.h>
#include <math.h>

// Problem constants (from reference setup_inputs)
#define Bq   16
#define Sq   1024
#define Hq   1024
#define Oq   256
#define Lq   4
#define NHq  8
#define DHq  128
#define Mq   (Bq*Sq)      // 16384 rows

typedef __bf16 bf16x8 __attribute__((ext_vector_type(8)));
typedef float  f32x4  __attribute__((ext_vector_type(4)));

__device__ __forceinline__ float bf2f(unsigned short u) {
    union { unsigned int i; float f; } x; x.i = ((unsigned int)u) << 16; return x.f;
}
__device__ __forceinline__ unsigned short f2bf(float f) {
    union { float f; unsigned int i; } x; x.f = f;
    unsigned int r = x.i + 0x7fffu + ((x.i >> 16) & 1u);   // RNE
    return (unsigned short)(r >> 16);
}

// ---------------- fp32 -> bf16 convert ----------------
__global__ void cvt_kernel(const float* __restrict__ src, unsigned short* __restrict__ dst, int n) {
    int i = blockIdx.x * 256 + threadIdx.x;
    if (i < n) dst[i] = f2bf(src[i]);
}

// ---------------- assemble per-layer [bf;bi;bh] bias (L x 3072) ----------------
__global__ void bias3_kernel(const float* __restrict__ bf_, const float* __restrict__ bi_,
                             const float* __restrict__ bh_, float* __restrict__ out) {
    int i = blockIdx.x * 256 + threadIdx.x;          // L*3H = 12288
    int l = i / (3*Hq); int r = i % (3*Hq); int g = r >> 10; int j = r & (Hq-1);
    const float* s = (g == 0) ? bf_ : (g == 1) ? bi_ : bh_;
    out[i] = s[l*Hq + j];
}

// ---------------- bf16 GEMM: C[M,N] = A[M,K] * W[N,K]^T + bias ----------------
// 128x128 tile, BK=32, 256 threads (4 waves 2x2, each wave 64x64 = 4x4 MFMA 16x16x32).
// LDS stride padded to 40 bf16 (80B) -> <=2-way bank aliasing on ds_read_b128 (free).
#define LDP 40
__global__ __launch_bounds__(256)
void gemm_bt_kernel(const unsigned short* __restrict__ A, const unsigned short* __restrict__ W,
                    const float* __restrict__ bias, void* __restrict__ C,
                    int N, int K, int out_bf16)
{
    __shared__ unsigned short As[128*LDP];
    __shared__ unsigned short Ws[128*LDP];
    const int tid  = threadIdx.x;
    const int bn   = blockIdx.x, bm = blockIdx.y;
    const int wid  = tid >> 6, lane = tid & 63;
    const int wm   = (wid >> 1) * 64, wn = (wid & 1) * 64;
    const int l15  = lane & 15, quad = lane >> 4;

    const unsigned short* Ag = A + (size_t)(bm*128) * K;
    const unsigned short* Wg = W + (size_t)(bn*128) * K;

    // staging: 128 rows x 32 cols = 512 chunks of 8 bf16 (16B); 2 chunks/thread
    const int c0 = tid, c1 = tid + 256;
    const int ar0 = c0 >> 2, ac0 = (c0 & 3) << 3;
    const int ar1 = c1 >> 2, ac1 = (c1 & 3) << 3;

    f32x4 acc[4][4] = {};

    for (int k0 = 0; k0 < K; k0 += 32) {
        uint4 a0 = *(const uint4*)(Ag + (size_t)ar0*K + k0 + ac0);
        uint4 a1 = *(const uint4*)(Ag + (size_t)ar1*K + k0 + ac1);
        uint4 w0 = *(const uint4*)(Wg + (size_t)ar0*K + k0 + ac0);
        uint4 w1 = *(const uint4*)(Wg + (size_t)ar1*K + k0 + ac1);
        __syncthreads();
        *(uint4*)&As[ar0*LDP + ac0] = a0;
        *(uint4*)&As[ar1*LDP + ac1] = a1;
        *(uint4*)&Ws[ar0*LDP + ac0] = w0;
        *(uint4*)&Ws[ar1*LDP + ac1] = w1;
        __syncthreads();
        bf16x8 af[4], wf[4];
        #pragma unroll
        for (int t = 0; t < 4; ++t) {
            af[t] = *(const bf16x8*)&As[(wm + t*16 + l15)*LDP + quad*8];
            wf[t] = *(const bf16x8*)&Ws[(wn + t*16 + l15)*LDP + quad*8];
        }
        #pragma unroll
        for (int tm = 0; tm < 4; ++tm)
            #pragma unroll
            for (int tn = 0; tn < 4; ++tn)
                acc[tm][tn] = __builtin_amdgcn_mfma_f32_16x16x32_bf16(af[tm], wf[tn], acc[tm][tn], 0, 0, 0);
    }

    // epilogue: C[row=(quad*4+r)][col=l15] per 16x16 tile (verified m89/m91 layout)
    #pragma unroll
    for (int tm = 0; tm < 4; ++tm) {
        int row0 = bm*128 + wm + tm*16 + quad*4;
        #pragma unroll
        for (int tn = 0; tn < 4; ++tn) {
            int col = bn*128 + wn + tn*16 + l15;
            float bv = bias ? bias[col] : 0.f;
            #pragma unroll
            for (int r = 0; r < 4; ++r) {
                float v = acc[tm][tn][r] + bv;
                size_t off = (size_t)(row0 + r) * N + col;
                if (out_bf16) ((unsigned short*)C)[off] = f2bf(v);
                else          ((float*)C)[off] = v;
            }
        }
    }
}

// ---------------- gates: fp = sig(f)/(sig(f)+sig(i)); add = sig(i)/(..)*ht ----------------
__global__ void gate_kernel(const unsigned short* __restrict__ G,
                            unsigned short* __restrict__ FPo, unsigned short* __restrict__ ADDo) {
    size_t idx = (size_t)blockIdx.x * 256 + threadIdx.x;   // over M*H
    int m = (int)(idx >> 10); int j = (int)(idx & 1023);
    size_t base = (size_t)m * 3072;
    float f = 1.f / (1.f + expf(-bf2f(G[base + j])));
    float i = 1.f / (1.f + expf(-bf2f(G[base + 1024 + j])));
    float ht = bf2f(G[base + 2048 + j]);
    float dn = f + i;
    FPo[idx]  = f2bf(f / dn);
    ADDo[idx] = f2bf((i / dn) * ht);
}

// ---------------- sequential scan: h_s = fp_s * h_{s-1} + add_s ----------------
__global__ void scan_kernel(const unsigned short* __restrict__ FP,
                            const unsigned short* __restrict__ ADD,
                            unsigned short* __restrict__ Ho) {
    int idx = blockIdx.x * 64 + threadIdx.x;               // B*H threads
    int b = idx >> 10, h = idx & 1023;
    size_t base = (size_t)b * Sq * Hq + h;
    float hc = 0.f;
    for (int s = 0; s < Sq; ++s) {
        size_t off = base + (size_t)s * Hq;
        hc = bf2f(FP[off]) * hc + bf2f(ADD[off]);
        Ho[off] = f2bf(hc);
    }
}

// ---------------- q projection at last position only ----------------
__global__ void qproj_kernel(const unsigned short* __restrict__ act,
                             const float* __restrict__ Wq, const float* __restrict__ bq,
                             float* __restrict__ q) {
    int b = blockIdx.x; int tid = threadIdx.x;
    __shared__ float xs[Hq];
    const unsigned short* xr = act + ((size_t)(b*Sq + Sq-1)) * Hq;
    for (int j = tid; j < Hq; j += 256) xs[j] = bf2f(xr[j]);
    __syncthreads();
    for (int k = 0; k < 4; ++k) {
        int n = tid + 256*k;
        const float4* wr = (const float4*)(Wq + (size_t)n * Hq);
        float a = 0.f;
        for (int c = 0; c < Hq/4; ++c) {
            float4 w = wr[c]; float4 xv = *(const float4*)&xs[c*4];
            a += w.x*xv.x + w.y*xv.y + w.z*xv.z + w.w*xv.w;
        }
        q[b*Hq + n] = a + bq[n];
    }
}

// ---------------- attention for the single last-position query ----------------
__global__ void attn_kernel(const unsigned short* __restrict__ KV,
                            const float* __restrict__ q, float* __restrict__ o) {
    int b = blockIdx.x >> 3, nh = blockIdx.x & 7;
    int tid = threadIdx.x;
    __shared__ float qs[DHq];
    __shared__ float p[Sq];
    __shared__ float red[256];
    if (tid < DHq) qs[tid] = q[b*Hq + nh*DHq + tid];
    __syncthreads();
    const float scale = 0.08838834764831845f;   // 1/sqrt(128)
    float lmax = -1e30f;
    float sc[4];
    for (int i = 0; i < 4; ++i) {
        int s = tid + 256*i;
        const unsigned short* kr = KV + ((size_t)(b*Sq + s)) * 2048 + nh*DHq;
        float a = 0.f;
        for (int c = 0; c < DHq/8; ++c) {
            union { uint4 v; unsigned short u[8]; } kk;
            kk.v = *(const uint4*)(kr + c*8);
            #pragma unroll
            for (int j = 0; j < 8; ++j) a += bf2f(kk.u[j]) * qs[c*8 + j];
        }
        a *= scale;
        sc[i] = a;
        lmax = fmaxf(lmax, a);
    }
    red[tid] = lmax; __syncthreads();
    for (int st = 128; st > 0; st >>= 1) { if (tid < st) red[tid] = fmaxf(red[tid], red[tid+st]); __syncthreads(); }
    float mx = red[0];
    __syncthreads();
    float lsum = 0.f;
    for (int i = 0; i < 4; ++i) {
        float e = expf(sc[i] - mx);
        p[tid + 256*i] = e;
        lsum += e;
    }
    red[tid] = lsum; __syncthreads();
    for (int st = 128; st > 0; st >>= 1) { if (tid < st) red[tid] += red[tid+st]; __syncthreads(); }
    float inv = 1.f / red[0];
    __syncthreads();
    // o_d = (1/sum) * sum_s p[s] * V[s,d]
    int d = tid & (DHq-1), half = tid >> 7;
    float acc = 0.f;
    for (int s = half*512; s < half*512 + 512; ++s)
        acc += p[s] * bf2f(KV[((size_t)(b*Sq + s)) * 2048 + 1024 + nh*DHq + d]);
    red[tid] = acc; __syncthreads();
    if (tid < DHq) o[b*Hq + nh*DHq + tid] = (red[tid] + red[tid + 128]) * inv;
}

// ---------------- out-proj + residual (last position) ----------------
__global__ void outproj_kernel(const float* __restrict__ o, const float* __restrict__ Wo,
                               const float* __restrict__ bo, const unsigned short* __restrict__ act,
                               float* __restrict__ resid) {
    int b = blockIdx.x; int tid = threadIdx.x;
    __shared__ float xs[Hq];
    for (int j = tid; j < Hq; j += 256) xs[j] = o[b*Hq + j];
    __syncthreads();
    const unsigned short* hr = act + ((size_t)(b*Sq + Sq-1)) * Hq;
    for (int k = 0; k < 4; ++k) {
        int n = tid + 256*k;
        const float4* wr = (const float4*)(Wo + (size_t)n * Hq);
        float a = 0.f;
        for (int c = 0; c < Hq/4; ++c) {
            float4 w = wr[c]; float4 xv = *(const float4*)&xs[c*4];
            a += w.x*xv.x + w.y*xv.y + w.z*xv.z + w.w*xv.w;
        }
        resid[b*Hq + n] = a + bo[n] + bf2f(hr[n]);
    }
}

// ---------------- final fc: out[b,o] = resid[b,:] . fc_w[o,:] + fc_b[o] ----------------
__global__ void fc_kernel(const float* __restrict__ resid, const float* __restrict__ Wfc,
                          const float* __restrict__ bfc, float* __restrict__ out) {
    int b = blockIdx.x; int tid = threadIdx.x;   // one thread per output (O=256)
    __shared__ float xs[Hq];
    for (int j = tid; j < Hq; j += 256) xs[j] = resid[b*Hq + j];
    __syncthreads();
    const float4* wr = (const float4*)(Wfc + (size_t)tid * Hq);
    float a = 0.f;
    for (int c = 0; c < Hq/4; ++c) {
        float4 w = wr[c]; float4 xv = *(const float4*)&xs[c*4];
        a += w.x*xv.x + w.y*xv.y + w.z*xv.z + w.w*xv.w;
    }
    out[b*Oq + tid] = a + bfc[tid];
}

extern "C" void kernel_launch(void* const* d_in, const int* in_sizes, int n_in,
                              void* d_out, int out_size, void* d_ws, size_t ws_size,
                              hipStream_t stream) {
    const float* x        = (const float*)d_in[0];
    const float* Wf       = (const float*)d_in[1];
    const float* bfv      = (const float*)d_in[2];
    const float* Wi       = (const float*)d_in[3];
    const float* biv      = (const float*)d_in[4];
    const float* Wh       = (const float*)d_in[5];
    const float* bhv      = (const float*)d_in[6];
    const float* in_proj_w= (const float*)d_in[7];
    const float* in_proj_b= (const float*)d_in[8];
    const float* out_w    = (const float*)d_in[9];
    const float* out_b    = (const float*)d_in[10];
    const float* fc_w     = (const float*)d_in[11];
    const float* fc_b     = (const float*)d_in[12];
    float* outp = (float*)d_out;

    const int HH = Hq*Hq;                       // 1,048,576

    // workspace carve (~265 MB total)
    char* p = (char*)d_ws;
    auto alloc = [&](size_t bytes) -> void* {
        void* r = (void*)p; p += (bytes + 255) & ~(size_t)255; return r;
    };
    unsigned short* Wcat = (unsigned short*)alloc((size_t)Lq*3*HH*2);   // 24 MB  bf16 [l][f;i;h][H][H]
    unsigned short* Wkv  = (unsigned short*)alloc((size_t)2048*1024*2); //  4 MB  bf16 K,V proj rows
    float*          Bias3= (float*)alloc((size_t)Lq*3*Hq*4);            // 48 KB
    unsigned short* actA = (unsigned short*)alloc((size_t)Mq*Hq*2);     // 32 MB
    unsigned short* actB = (unsigned short*)alloc((size_t)Mq*Hq*2);     // 32 MB
    unsigned short* Gpre = (unsigned short*)alloc((size_t)Mq*3*Hq*2);   // 96 MB  bf16 gate preacts
    unsigned short* FPg  = (unsigned short*)alloc((size_t)Mq*Hq*2);     // 32 MB
    unsigned short* ADDg = (unsigned short*)alloc((size_t)Mq*Hq*2);     // 32 MB
    unsigned short* KV   = Gpre;                                        // alias: used after layers done
    float* qbuf = (float*)alloc((size_t)Bq*Hq*4);
    float* obuf = (float*)alloc((size_t)Bq*Hq*4);
    float* rbuf = (float*)alloc((size_t)Bq*Hq*4);

    // --- conversions (every call; graph-safe) ---
    cvt_kernel<<<Mq*Hq/256, 256, 0, stream>>>(x, actA, Mq*Hq);
    for (int l = 0; l < Lq; ++l) {
        cvt_kernel<<<HH/256, 256, 0, stream>>>(Wf + (size_t)l*HH, Wcat + (size_t)l*3*HH,          HH);
        cvt_kernel<<<HH/256, 256, 0, stream>>>(Wi + (size_t)l*HH, Wcat + (size_t)l*3*HH + HH,     HH);
        cvt_kernel<<<HH/256, 256, 0, stream>>>(Wh + (size_t)l*HH, Wcat + (size_t)l*3*HH + 2*HH,   HH);
    }
    cvt_kernel<<<2048*1024/256, 256, 0, stream>>>(in_proj_w + (size_t)Hq*Hq, Wkv, 2048*1024);
    bias3_kernel<<<(Lq*3*Hq)/256, 256, 0, stream>>>(bfv, biv, bhv, Bias3);

    // --- minLSTM layers ---
    unsigned short* cur = actA;
    unsigned short* nxt = actB;
    for (int l = 0; l < Lq; ++l) {
        gemm_bt_kernel<<<dim3(3*Hq/128, Mq/128), 256, 0, stream>>>(
            cur, Wcat + (size_t)l*3*HH, Bias3 + l*3*Hq, Gpre, 3*Hq, Hq, 1);
        gate_kernel<<<Mq*Hq/256, 256, 0, stream>>>(Gpre, FPg, ADDg);
        scan_kernel<<<Bq*Hq/64, 64, 0, stream>>>(FPg, ADDg, nxt);
        unsigned short* t = cur; cur = nxt; nxt = t;
    }

    // --- attention (only last-position query matters) ---
    gemm_bt_kernel<<<dim3(2048/128, Mq/128), 256, 0, stream>>>(
        cur, Wkv, in_proj_b + Hq, KV, 2048, Hq, 1);
    qproj_kernel<<<Bq, 256, 0, stream>>>(cur, in_proj_w, in_proj_b, qbuf);
    attn_kernel<<<Bq*NHq, 256, 0, stream>>>(KV, qbuf, obuf);
    outproj_kernel<<<Bq, 256, 0, stream>>>(obuf, out_w, out_b, cur, rbuf);
    fc_kernel<<<Bq, 256, 0, stream>>>(rbuf, fc_w, fc_b, outp);
}

// Round 2
// 1238.391 us; speedup vs baseline: 1.6578x; 1.6578x over previous
//
#include <hip/hip_runtime.h>
#include <hip/hip_bf16.h>
#include <math.h>

// Problem constants (from reference setup_inputs)
#define Bq   16
#define Sq   1024
#define Hq   1024
#define Oq   256
#define Lq   4
#define NHq  8
#define DHq  128
#define Mq   (Bq*Sq)      // 16384 rows
#define HHq  (Hq*Hq)      // 1048576
#define NCc  32           // scan chunks
#define CTc  32           // timesteps per chunk

typedef __bf16 bf16x8 __attribute__((ext_vector_type(8)));
typedef float  f32x4  __attribute__((ext_vector_type(4)));

__device__ __forceinline__ float bf2f(unsigned int u) {
    union { unsigned int i; float f; } x; x.i = u << 16; return x.f;
}
__device__ __forceinline__ unsigned short f2bf(float f) {
    union { float f; unsigned int i; } x; x.f = f;
    unsigned int r = x.i + 0x7fffu + ((x.i >> 16) & 1u);   // RNE
    return (unsigned short)(r >> 16);
}
__device__ __forceinline__ float sigm(float x) { return 1.f / (1.f + __expf(-x)); }

// ---------------- fp32 -> bf16 convert ----------------
__global__ void cvt_kernel(const float* __restrict__ src, unsigned short* __restrict__ dst, int n) {
    int i = blockIdx.x * 256 + threadIdx.x;
    if (i < n) dst[i] = f2bf(src[i]);
}

// ---------------- fused weight convert: Wcat[l][f;i;h][H][H] ----------------
__global__ void cvtW_kernel(const float* __restrict__ Wf, const float* __restrict__ Wi,
                            const float* __restrict__ Wh, unsigned short* __restrict__ Wcat) {
    int i = blockIdx.x * 256 + threadIdx.x;     // L*3*HH
    int l = (i >> 20) / 3;
    int r = i - l * 3 * HHq;
    int g = r >> 20; int j = r & (HHq - 1);
    const float* s = (g == 0) ? Wf : (g == 1) ? Wi : Wh;
    Wcat[i] = f2bf(s[(size_t)l * HHq + j]);
}

// ---------------- assemble per-layer [bf;bi;bh] bias (L x 3072) ----------------
__global__ void bias3_kernel(const float* __restrict__ bf_, const float* __restrict__ bi_,
                             const float* __restrict__ bh_, float* __restrict__ out) {
    int i = blockIdx.x * 256 + threadIdx.x;          // L*3H = 12288
    int l = i / (3*Hq); int r = i % (3*Hq); int g = r >> 10; int j = r & (Hq-1);
    const float* s = (g == 0) ? bf_ : (g == 1) ? bi_ : bh_;
    out[i] = s[l*Hq + j];
}

// ---------------- bf16 GEMM: C[M,N] = A[M,K] * W[N,K]^T + bias (bf16 out) ----------------
// 128x128 tile, BK=32, 4 waves 2x2, global_load_lds width=16 staging.
// LDS unpadded [128][32]; XOR chunk swizzle c' = c ^ ((r>>1)&3) -> 2-way (free) ds_read_b128.
__device__ __forceinline__ void gl2lds16(const unsigned short* g, unsigned short* l) {
    __builtin_amdgcn_global_load_lds((const __attribute__((address_space(1))) void*)g,
                                     (__attribute__((address_space(3))) void*)l, 16, 0, 0);
}

__global__ __launch_bounds__(256)
void gemm_bt_kernel(const unsigned short* __restrict__ A, const unsigned short* __restrict__ W,
                    const float* __restrict__ bias, unsigned short* __restrict__ C,
                    int N, int K)
{
    __shared__ unsigned short As[128*32];
    __shared__ unsigned short Ws[128*32];
    const int tid  = threadIdx.x;
    const int bn   = blockIdx.x, bm = blockIdx.y;
    const int wid  = tid >> 6, lane = tid & 63;
    const int wm   = (wid >> 1) * 64, wn = (wid & 1) * 64;
    const int l15  = lane & 15, quad = lane >> 4;

    const unsigned short* Ag = A + (size_t)(bm*128) * K;
    const unsigned short* Wg = W + (size_t)(bn*128) * K;

    // staging: wave w covers rows [w*32, w*32+32); lane l -> row rbase + (l>>2), slot chunk l&3.
    // slot (r,c') holds global chunk c = c' ^ ((r>>1)&3); note ((r0+16)>>1)&3 == ((r0)>>1)&3.
    const int r0     = wid*32 + (lane >> 2);
    const int cst    = (lane & 3) ^ ((r0 >> 1) & 3);
    const size_t g0  = (size_t)r0 * K + cst*8;
    const size_t g1  = (size_t)(r0 + 16) * K + cst*8;
    unsigned short* lA0 = &As[wid*1024];
    unsigned short* lA1 = &As[wid*1024 + 512];
    unsigned short* lW0 = &Ws[wid*1024];
    unsigned short* lW1 = &Ws[wid*1024 + 512];

    // fragment read: row r = (mult of 16)+l15 -> f(r) = (l15>>1)&3, same for all tiles
    const int crd = quad ^ ((l15 >> 1) & 3);

    f32x4 acc[4][4] = {};

    for (int k0 = 0; k0 < K; k0 += 32) {
        __syncthreads();                       // prior ds_reads done before overwrite
        gl2lds16(Ag + g0 + k0, lA0);
        gl2lds16(Ag + g1 + k0, lA1);
        gl2lds16(Wg + g0 + k0, lW0);
        gl2lds16(Wg + g1 + k0, lW1);
        __syncthreads();                       // vmcnt(0) drain + visibility
        bf16x8 af[4], wf[4];
        #pragma unroll
        for (int t = 0; t < 4; ++t) {
            af[t] = *(const bf16x8*)&As[(wm + t*16 + l15)*32 + crd*8];
            wf[t] = *(const bf16x8*)&Ws[(wn + t*16 + l15)*32 + crd*8];
        }
        #pragma unroll
        for (int tm = 0; tm < 4; ++tm)
            #pragma unroll
            for (int tn = 0; tn < 4; ++tn)
                acc[tm][tn] = __builtin_amdgcn_mfma_f32_16x16x32_bf16(af[tm], wf[tn], acc[tm][tn], 0, 0, 0);
    }

    // epilogue: C[row=quad*4+r][col=l15] per 16x16 tile (verified m89/m91 layout)
    #pragma unroll
    for (int tm = 0; tm < 4; ++tm) {
        int row0 = bm*128 + wm + tm*16 + quad*4;
        #pragma unroll
        for (int tn = 0; tn < 4; ++tn) {
            int col = bn*128 + wn + tn*16 + l15;
            float bv = bias[col];
            #pragma unroll
            for (int r = 0; r < 4; ++r)
                C[(size_t)(row0 + r) * N + col] = f2bf(acc[tm][tn][r] + bv);
        }
    }
}

// ---------------- fused gate + chunked scan ----------------
// Gate math: f=sig(gf), i=sig(gi); fp=f/(f+i); add=i/(f+i)*gh. h_s = fp*h_{s-1}+add.
// Pass A: per (b,chunk,j-pair): P = prod fp, Aagg = local scan from h=0. 1024 blocks.
__global__ __launch_bounds__(256)
void scan_sum_kernel(const unsigned short* __restrict__ G,
                     float* __restrict__ Ps, float* __restrict__ Asum) {
    int bid = blockIdx.x;                    // B*NC*2 = 1024
    int tid = threadIdx.x;
    int b = bid >> 6; int r = bid & 63; int chunk = r >> 1; int jb = r & 1;
    int j = jb*512 + tid*2;
    size_t base = ((size_t)(b*Sq + chunk*CTc)) * 3072 + j;
    float P0 = 1.f, P1 = 1.f, A0 = 0.f, A1 = 0.f;
    for (int s = 0; s < CTc; ++s) {
        size_t ro = base + (size_t)s * 3072;
        unsigned int uf = *(const unsigned int*)(G + ro);
        unsigned int ui = *(const unsigned int*)(G + ro + 1024);
        unsigned int uh = *(const unsigned int*)(G + ro + 2048);
        float f0 = sigm(bf2f(uf & 0xffffu)), f1 = sigm(bf2f(uf >> 16));
        float i0 = sigm(bf2f(ui & 0xffffu)), i1 = sigm(bf2f(ui >> 16));
        float h0 = bf2f(uh & 0xffffu),       h1 = bf2f(uh >> 16);
        float rd0 = 1.f / (f0 + i0),         rd1 = 1.f / (f1 + i1);
        float fp0 = f0 * rd0,                fp1 = f1 * rd1;
        float ad0 = i0 * rd0 * h0,           ad1 = i1 * rd1 * h1;
        P0 *= fp0; A0 = fp0 * A0 + ad0;
        P1 *= fp1; A1 = fp1 * A1 + ad1;
    }
    int oi = (b*NCc + chunk)*Hq + j;
    Ps[oi] = P0; Ps[oi+1] = P1;
    Asum[oi] = A0; Asum[oi+1] = A1;
}

// Pass B: chunk-level prefix. h entering chunk c stored to Hb.
__global__ void scan_base_kernel(const float* __restrict__ Ps, const float* __restrict__ Asum,
                                 float* __restrict__ Hb) {
    int t = blockIdx.x * 256 + threadIdx.x;  // B*H = 16384
    int b = t >> 10, j = t & 1023;
    float h = 0.f;
    for (int c = 0; c < NCc; ++c) {
        int idx = (b*NCc + c)*Hq + j;
        Hb[idx] = h;
        h = Ps[idx] * h + Asum[idx];
    }
}

// Pass C: recompute gates, scan with correct init, write bf16 h.
__global__ __launch_bounds__(256)
void scan_out_kernel(const unsigned short* __restrict__ G, const float* __restrict__ Hb,
                     unsigned short* __restrict__ Ho) {
    int bid = blockIdx.x;                    // B*NC*2 = 1024
    int tid = threadIdx.x;
    int b = bid >> 6; int r = bid & 63; int chunk = r >> 1; int jb = r & 1;
    int j = jb*512 + tid*2;
    size_t base = ((size_t)(b*Sq + chunk*CTc)) * 3072 + j;
    int oi = (b*NCc + chunk)*Hq + j;
    float h0 = Hb[oi], h1 = Hb[oi+1];
    for (int s = 0; s < CTc; ++s) {
        size_t ro = base + (size_t)s * 3072;
        unsigned int uf = *(const unsigned int*)(G + ro);
        unsigned int ui = *(const unsigned int*)(G + ro + 1024);
        unsigned int uh = *(const unsigned int*)(G + ro + 2048);
        float f0 = sigm(bf2f(uf & 0xffffu)), f1 = sigm(bf2f(uf >> 16));
        float i0 = sigm(bf2f(ui & 0xffffu)), i1 = sigm(bf2f(ui >> 16));
        float g0 = bf2f(uh & 0xffffu),       g1 = bf2f(uh >> 16);
        float rd0 = 1.f / (f0 + i0),         rd1 = 1.f / (f1 + i1);
        h0 = f0 * rd0 * h0 + i0 * rd0 * g0;
        h1 = f1 * rd1 * h1 + i1 * rd1 * g1;
        unsigned int packed = (unsigned int)f2bf(h0) | ((unsigned int)f2bf(h1) << 16);
        *(unsigned int*)(Ho + (size_t)(b*Sq + chunk*CTc + s) * Hq + j) = packed;
    }
}

// ---------------- extract last-position activations as fp32 ----------------
__global__ void xlast_kernel(const unsigned short* __restrict__ act, float* __restrict__ xl) {
    int i = blockIdx.x * 256 + threadIdx.x;  // B*H
    int b = i >> 10, j = i & 1023;
    xl[i] = bf2f((unsigned int)act[((size_t)(b*Sq + Sq-1)) * Hq + j]);
}

// ---------------- wave-per-row GEMV: out[b,n] = W[n,:].x[b,:] + bias[n] (+resid[b,n]) ----------------
__global__ __launch_bounds__(256)
void gemv_kernel(const float* __restrict__ W, const float* __restrict__ xv,
                 const float* __restrict__ bias, const float* __restrict__ resid,
                 float* __restrict__ out, int N) {
    int b = blockIdx.x;
    int w = threadIdx.x >> 6, lane = threadIdx.x & 63;
    int n = blockIdx.y*4 + w;
    __shared__ float xs[Hq];
    *(float4*)&xs[threadIdx.x*4] = *(const float4*)&xv[(size_t)b*Hq + threadIdx.x*4];
    __syncthreads();
    const float4* wr = (const float4*)(W + (size_t)n * Hq);
    float a = 0.f;
    #pragma unroll
    for (int c = 0; c < 4; ++c) {
        float4 wv = wr[c*64 + lane];
        float4 x4 = *(const float4*)&xs[c*256 + lane*4];
        a += wv.x*x4.x + wv.y*x4.y + wv.z*x4.z + wv.w*x4.w;
    }
    #pragma unroll
    for (int st = 32; st > 0; st >>= 1) a += __shfl_xor(a, st, 64);
    if (lane == 0) out[(size_t)b*N + n] = a + bias[n] + (resid ? resid[(size_t)b*Hq + n] : 0.f);
}

// ---------------- attention for the single last-position query ----------------
__global__ void attn_kernel(const unsigned short* __restrict__ KV,
                            const float* __restrict__ q, float* __restrict__ o) {
    int b = blockIdx.x >> 3, nh = blockIdx.x & 7;
    int tid = threadIdx.x;
    __shared__ float qs[DHq];
    __shared__ float p[Sq];
    __shared__ float red[256];
    if (tid < DHq) qs[tid] = q[b*Hq + nh*DHq + tid];
    __syncthreads();
    const float scale = 0.08838834764831845f;   // 1/sqrt(128)
    float lmax = -1e30f;
    float sc[4];
    for (int i = 0; i < 4; ++i) {
        int s = tid + 256*i;
        const unsigned short* kr = KV + ((size_t)(b*Sq + s)) * 2048 + nh*DHq;
        float a = 0.f;
        for (int c = 0; c < DHq/8; ++c) {
            union { uint4 v; unsigned short u[8]; } kk;
            kk.v = *(const uint4*)(kr + c*8);
            #pragma unroll
            for (int jx = 0; jx < 8; ++jx) a += bf2f((unsigned int)kk.u[jx]) * qs[c*8 + jx];
        }
        a *= scale;
        sc[i] = a;
        lmax = fmaxf(lmax, a);
    }
    red[tid] = lmax; __syncthreads();
    for (int st = 128; st > 0; st >>= 1) { if (tid < st) red[tid] = fmaxf(red[tid], red[tid+st]); __syncthreads(); }
    float mx = red[0];
    __syncthreads();
    float lsum = 0.f;
    for (int i = 0; i < 4; ++i) {
        float e = __expf(sc[i] - mx);
        p[tid + 256*i] = e;
        lsum += e;
    }
    red[tid] = lsum; __syncthreads();
    for (int st = 128; st > 0; st >>= 1) { if (tid < st) red[tid] += red[tid+st]; __syncthreads(); }
    float inv = 1.f / red[0];
    __syncthreads();
    int d = tid & (DHq-1), half = tid >> 7;
    float acc = 0.f;
    for (int s = half*512; s < half*512 + 512; ++s)
        acc += p[s] * bf2f((unsigned int)KV[((size_t)(b*Sq + s)) * 2048 + 1024 + nh*DHq + d]);
    red[tid] = acc; __syncthreads();
    if (tid < DHq) o[b*Hq + nh*DHq + tid] = (red[tid] + red[tid + 128]) * inv;
}

extern "C" void kernel_launch(void* const* d_in, const int* in_sizes, int n_in,
                              void* d_out, int out_size, void* d_ws, size_t ws_size,
                              hipStream_t stream) {
    const float* x        = (const float*)d_in[0];
    const float* Wf       = (const float*)d_in[1];
    const float* bfv      = (const float*)d_in[2];
    const float* Wi       = (const float*)d_in[3];
    const float* biv      = (const float*)d_in[4];
    const float* Wh       = (const float*)d_in[5];
    const float* bhv      = (const float*)d_in[6];
    const float* in_proj_w= (const float*)d_in[7];
    const float* in_proj_b= (const float*)d_in[8];
    const float* out_w    = (const float*)d_in[9];
    const float* out_b    = (const float*)d_in[10];
    const float* fc_w     = (const float*)d_in[11];
    const float* fc_b     = (const float*)d_in[12];
    float* outp = (float*)d_out;

    // workspace carve (~196 MB)
    char* p = (char*)d_ws;
    auto alloc = [&](size_t bytes) -> void* {
        void* r = (void*)p; p += (bytes + 255) & ~(size_t)255; return r;
    };
    unsigned short* Wcat = (unsigned short*)alloc((size_t)Lq*3*HHq*2);  // 24 MB
    unsigned short* Wkv  = (unsigned short*)alloc((size_t)2048*Hq*2);   //  4 MB
    float*          Bias3= (float*)alloc((size_t)Lq*3*Hq*4);            // 48 KB
    unsigned short* actA = (unsigned short*)alloc((size_t)Mq*Hq*2);     // 32 MB
    unsigned short* actB = (unsigned short*)alloc((size_t)Mq*Hq*2);     // 32 MB
    unsigned short* Gpre = (unsigned short*)alloc((size_t)Mq*3*Hq*2);   // 96 MB
    float* Ps   = (float*)alloc((size_t)Bq*NCc*Hq*4);                   //  2 MB
    float* Asum = (float*)alloc((size_t)Bq*NCc*Hq*4);                   //  2 MB
    float* Hb   = (float*)alloc((size_t)Bq*NCc*Hq*4);                   //  2 MB
    unsigned short* KV = Gpre;                                          // alias (post-layers)
    float* xl   = (float*)alloc((size_t)Bq*Hq*4);
    float* qbuf = (float*)alloc((size_t)Bq*Hq*4);
    float* obuf = (float*)alloc((size_t)Bq*Hq*4);
    float* rbuf = (float*)alloc((size_t)Bq*Hq*4);

    // --- conversions ---
    cvt_kernel<<<Mq*Hq/256, 256, 0, stream>>>(x, actA, Mq*Hq);
    cvtW_kernel<<<Lq*3*HHq/256, 256, 0, stream>>>(Wf, Wi, Wh, Wcat);
    cvt_kernel<<<2048*Hq/256, 256, 0, stream>>>(in_proj_w + (size_t)Hq*Hq, Wkv, 2048*Hq);
    bias3_kernel<<<(Lq*3*Hq)/256, 256, 0, stream>>>(bfv, biv, bhv, Bias3);

    // --- minLSTM layers ---
    unsigned short* cur = actA;
    unsigned short* nxt = actB;
    for (int l = 0; l < Lq; ++l) {
        gemm_bt_kernel<<<dim3(3*Hq/128, Mq/128), 256, 0, stream>>>(
            cur, Wcat + (size_t)l*3*HHq, Bias3 + l*3*Hq, Gpre, 3*Hq, Hq);
        scan_sum_kernel<<<Bq*NCc*2, 256, 0, stream>>>(Gpre, Ps, Asum);
        scan_base_kernel<<<Bq*Hq/256, 256, 0, stream>>>(Ps, Asum, Hb);
        scan_out_kernel<<<Bq*NCc*2, 256, 0, stream>>>(Gpre, Hb, nxt);
        unsigned short* t = cur; cur = nxt; nxt = t;
    }

    // --- attention (only last-position query matters) ---
    gemm_bt_kernel<<<dim3(2048/128, Mq/128), 256, 0, stream>>>(
        cur, Wkv, in_proj_b + Hq, KV, 2048, Hq);
    xlast_kernel<<<Bq*Hq/256, 256, 0, stream>>>(cur, xl);
    gemv_kernel<<<dim3(Bq, Hq/4), 256, 0, stream>>>(in_proj_w, xl, in_proj_b, nullptr, qbuf, Hq);
    attn_kernel<<<Bq*NHq, 256, 0, stream>>>(KV, qbuf, obuf);
    gemv_kernel<<<dim3(Bq, Hq/4), 256, 0, stream>>>(out_w, obuf, out_b, xl, rbuf, Hq);
    gemv_kernel<<<dim3(Bq, Oq/4), 256, 0, stream>>>(fc_w, rbuf, fc_b, nullptr, outp, Oq);
}

// Round 3
// 1167.341 us; speedup vs baseline: 1.7587x; 1.0609x over previous
//
#include <hip/hip_runtime.h>
#include <hip/hip_bf16.h>
#include <math.h>

// Problem constants (from reference setup_inputs)
#define Bq   16
#define Sq   1024
#define Hq   1024
#define Oq   256
#define Lq   4
#define NHq  8
#define DHq  128
#define Mq   (Bq*Sq)      // 16384 rows
#define HHq  (Hq*Hq)      // 1048576
#define NCc  32           // scan chunks
#define CTc  32           // timesteps per chunk

typedef __bf16 bf16x8 __attribute__((ext_vector_type(8)));
typedef float  f32x4  __attribute__((ext_vector_type(4)));

__device__ __forceinline__ float bf2f(unsigned int u) {
    union { unsigned int i; float f; } x; x.i = u << 16; return x.f;
}
__device__ __forceinline__ unsigned short f2bf(float f) {
    union { float f; unsigned int i; } x; x.f = f;
    unsigned int r = x.i + 0x7fffu + ((x.i >> 16) & 1u);   // RNE
    return (unsigned short)(r >> 16);
}
__device__ __forceinline__ float sigm(float x) { return 1.f / (1.f + __expf(-x)); }

// ---------------- fp32 -> bf16 convert ----------------
__global__ void cvt_kernel(const float* __restrict__ src, unsigned short* __restrict__ dst, int n) {
    int i = blockIdx.x * 256 + threadIdx.x;
    if (i < n) dst[i] = f2bf(src[i]);
}

// ---------------- fused weight convert: Wcat[l][f;i;h][H][H] ----------------
__global__ void cvtW_kernel(const float* __restrict__ Wf, const float* __restrict__ Wi,
                            const float* __restrict__ Wh, unsigned short* __restrict__ Wcat) {
    int i = blockIdx.x * 256 + threadIdx.x;     // L*3*HH
    int l = (i >> 20) / 3;
    int r = i - l * 3 * HHq;
    int g = r >> 20; int j = r & (HHq - 1);
    const float* s = (g == 0) ? Wf : (g == 1) ? Wi : Wh;
    Wcat[i] = f2bf(s[(size_t)l * HHq + j]);
}

// ---------------- assemble per-layer [bf;bi;bh] bias (L x 3072) ----------------
__global__ void bias3_kernel(const float* __restrict__ bf_, const float* __restrict__ bi_,
                             const float* __restrict__ bh_, float* __restrict__ out) {
    int i = blockIdx.x * 256 + threadIdx.x;          // L*3H = 12288
    int l = i / (3*Hq); int r = i % (3*Hq); int g = r >> 10; int j = r & (Hq-1);
    const float* s = (g == 0) ? bf_ : (g == 1) ? bi_ : bh_;
    out[i] = s[l*Hq + j];
}

// ---------------- bf16 GEMM: C[M,N] = A[M,K] * W[N,K]^T + bias (bf16 out) ----------------
// 128x128 tile, BK=32, 4 waves 2x2, global_load_lds width=16 staging, XOR-swizzled LDS.
// Epilogue: C-tile staged through LDS (2 x 64-row halves, XOR chunk swizzle) ->
// 4 coalesced global_store_dwordx4 per thread instead of 64 scalar 2B stores.
__device__ __forceinline__ void gl2lds16(const unsigned short* g, unsigned short* l) {
    __builtin_amdgcn_global_load_lds((const __attribute__((address_space(1))) void*)g,
                                     (__attribute__((address_space(3))) void*)l, 16, 0, 0);
}

__global__ __launch_bounds__(256)
void gemm_bt_kernel(const unsigned short* __restrict__ A, const unsigned short* __restrict__ W,
                    const float* __restrict__ bias, unsigned short* __restrict__ C,
                    int N, int K)
{
    __shared__ unsigned short smem[8192];    // 16KB: As=[0,4096), Ws=[4096,8192); epilogue reuses all
    unsigned short* As = smem;
    unsigned short* Ws = smem + 4096;
    const int tid  = threadIdx.x;
    const int bn   = blockIdx.x, bm = blockIdx.y;
    const int wid  = tid >> 6, lane = tid & 63;
    const int wm   = (wid >> 1) * 64, wn = (wid & 1) * 64;
    const int l15  = lane & 15, quad = lane >> 4;

    const unsigned short* Ag = A + (size_t)(bm*128) * K;
    const unsigned short* Wg = W + (size_t)(bn*128) * K;

    // staging: wave w covers rows [w*32, w*32+32); lane l -> row rbase + (l>>2), slot chunk l&3.
    // slot (r,c') holds global chunk c = c' ^ ((r>>1)&3); note ((r0+16)>>1)&3 == ((r0)>>1)&3.
    const int r0     = wid*32 + (lane >> 2);
    const int cst    = (lane & 3) ^ ((r0 >> 1) & 3);
    const size_t g0  = (size_t)r0 * K + cst*8;
    const size_t g1  = (size_t)(r0 + 16) * K + cst*8;
    unsigned short* lA0 = &As[wid*1024];
    unsigned short* lA1 = &As[wid*1024 + 512];
    unsigned short* lW0 = &Ws[wid*1024];
    unsigned short* lW1 = &Ws[wid*1024 + 512];

    // fragment read: row r = (mult of 16)+l15 -> swizzle key (l15>>1)&3, same for all tiles
    const int crd = quad ^ ((l15 >> 1) & 3);

    f32x4 acc[4][4] = {};

    for (int k0 = 0; k0 < K; k0 += 32) {
        __syncthreads();                       // prior ds_reads done before overwrite
        gl2lds16(Ag + g0 + k0, lA0);
        gl2lds16(Ag + g1 + k0, lA1);
        gl2lds16(Wg + g0 + k0, lW0);
        gl2lds16(Wg + g1 + k0, lW1);
        __syncthreads();                       // vmcnt(0) drain + visibility
        bf16x8 af[4], wf[4];
        #pragma unroll
        for (int t = 0; t < 4; ++t) {
            af[t] = *(const bf16x8*)&As[(wm + t*16 + l15)*32 + crd*8];
            wf[t] = *(const bf16x8*)&Ws[(wn + t*16 + l15)*32 + crd*8];
        }
        #pragma unroll
        for (int tm = 0; tm < 4; ++tm)
            #pragma unroll
            for (int tn = 0; tn < 4; ++tn)
                acc[tm][tn] = __builtin_amdgcn_mfma_f32_16x16x32_bf16(af[tm], wf[tn], acc[tm][tn], 0, 0, 0);
    }

    // ---- epilogue via LDS transpose ----
    float bv[4];
    #pragma unroll
    for (int tn = 0; tn < 4; ++tn) bv[tn] = bias[bn*128 + wn + tn*16 + l15];

    const int rl_rd = tid >> 2, cq = tid & 3;
    #pragma unroll
    for (int h = 0; h < 2; ++h) {
        __syncthreads();                       // LDS free (K-loop / previous half reads done)
        if ((wm >> 6) == h) {
            #pragma unroll
            for (int tm = 0; tm < 4; ++tm) {
                #pragma unroll
                for (int tn = 0; tn < 4; ++tn) {
                    int col = wn + tn*16 + l15;
                    int cc = col >> 3, w8 = col & 7;
                    #pragma unroll
                    for (int r = 0; r < 4; ++r) {
                        int rl = tm*16 + quad*4 + r;          // 0..63 local row
                        smem[rl*128 + ((cc ^ (rl & 7)) << 3) + w8] = f2bf(acc[tm][tn][r] + bv[tn]);
                    }
                }
            }
        }
        __syncthreads();
        size_t grow = (size_t)(bm*128 + h*64 + rl_rd) * N + bn*128 + cq*32;
        #pragma unroll
        for (int k = 0; k < 4; ++k) {
            int cc = cq*4 + k;
            uint4 v = *(const uint4*)&smem[rl_rd*128 + ((cc ^ (rl_rd & 7)) << 3)];
            *(uint4*)&C[grow + k*8] = v;
        }
    }
}

// ---------------- fused gate + chunked scan ----------------
// Pass A: per (b,chunk,j-pair): P = prod fp, Aagg = local scan from h=0. 1024 blocks.
__global__ __launch_bounds__(256)
void scan_sum_kernel(const unsigned short* __restrict__ G,
                     float* __restrict__ Ps, float* __restrict__ Asum) {
    int bid = blockIdx.x;                    // B*NC*2 = 1024
    int tid = threadIdx.x;
    int b = bid >> 6; int r = bid & 63; int chunk = r >> 1; int jb = r & 1;
    int j = jb*512 + tid*2;
    size_t base = ((size_t)(b*Sq + chunk*CTc)) * 3072 + j;
    float P0 = 1.f, P1 = 1.f, A0 = 0.f, A1 = 0.f;
    for (int s = 0; s < CTc; ++s) {
        size_t ro = base + (size_t)s * 3072;
        unsigned int uf = *(const unsigned int*)(G + ro);
        unsigned int ui = *(const unsigned int*)(G + ro + 1024);
        unsigned int uh = *(const unsigned int*)(G + ro + 2048);
        float f0 = sigm(bf2f(uf & 0xffffu)), f1 = sigm(bf2f(uf >> 16));
        float i0 = sigm(bf2f(ui & 0xffffu)), i1 = sigm(bf2f(ui >> 16));
        float h0 = bf2f(uh & 0xffffu),       h1 = bf2f(uh >> 16);
        float rd0 = 1.f / (f0 + i0),         rd1 = 1.f / (f1 + i1);
        float fp0 = f0 * rd0,                fp1 = f1 * rd1;
        float ad0 = i0 * rd0 * h0,           ad1 = i1 * rd1 * h1;
        P0 *= fp0; A0 = fp0 * A0 + ad0;
        P1 *= fp1; A1 = fp1 * A1 + ad1;
    }
    int oi = (b*NCc + chunk)*Hq + j;
    Ps[oi] = P0; Ps[oi+1] = P1;
    Asum[oi] = A0; Asum[oi+1] = A1;
}

// Pass B: chunk-level prefix. h entering chunk c stored to Hb.
__global__ void scan_base_kernel(const float* __restrict__ Ps, const float* __restrict__ Asum,
                                 float* __restrict__ Hb) {
    int t = blockIdx.x * 256 + threadIdx.x;  // B*H = 16384
    int b = t >> 10, j = t & 1023;
    float h = 0.f;
    for (int c = 0; c < NCc; ++c) {
        int idx = (b*NCc + c)*Hq + j;
        Hb[idx] = h;
        h = Ps[idx] * h + Asum[idx];
    }
}

// Pass C: recompute gates, scan with correct init, write bf16 h.
__global__ __launch_bounds__(256)
void scan_out_kernel(const unsigned short* __restrict__ G, const float* __restrict__ Hb,
                     unsigned short* __restrict__ Ho) {
    int bid = blockIdx.x;                    // B*NC*2 = 1024
    int tid = threadIdx.x;
    int b = bid >> 6; int r = bid & 63; int chunk = r >> 1; int jb = r & 1;
    int j = jb*512 + tid*2;
    size_t base = ((size_t)(b*Sq + chunk*CTc)) * 3072 + j;
    int oi = (b*NCc + chunk)*Hq + j;
    float h0 = Hb[oi], h1 = Hb[oi+1];
    for (int s = 0; s < CTc; ++s) {
        size_t ro = base + (size_t)s * 3072;
        unsigned int uf = *(const unsigned int*)(G + ro);
        unsigned int ui = *(const unsigned int*)(G + ro + 1024);
        unsigned int uh = *(const unsigned int*)(G + ro + 2048);
        float f0 = sigm(bf2f(uf & 0xffffu)), f1 = sigm(bf2f(uf >> 16));
        float i0 = sigm(bf2f(ui & 0xffffu)), i1 = sigm(bf2f(ui >> 16));
        float g0 = bf2f(uh & 0xffffu),       g1 = bf2f(uh >> 16);
        float rd0 = 1.f / (f0 + i0),         rd1 = 1.f / (f1 + i1);
        h0 = f0 * rd0 * h0 + i0 * rd0 * g0;
        h1 = f1 * rd1 * h1 + i1 * rd1 * g1;
        unsigned int packed = (unsigned int)f2bf(h0) | ((unsigned int)f2bf(h1) << 16);
        *(unsigned int*)(Ho + (size_t)(b*Sq + chunk*CTc + s) * Hq + j) = packed;
    }
}

// ---------------- extract last-position activations as fp32 ----------------
__global__ void xlast_kernel(const unsigned short* __restrict__ act, float* __restrict__ xl) {
    int i = blockIdx.x * 256 + threadIdx.x;  // B*H
    int b = i >> 10, j = i & 1023;
    xl[i] = bf2f((unsigned int)act[((size_t)(b*Sq + Sq-1)) * Hq + j]);
}

// ---------------- wave-per-row GEMV: out[b,n] = W[n,:].x[b,:] + bias[n] (+resid[b,n]) ----------------
__global__ __launch_bounds__(256)
void gemv_kernel(const float* __restrict__ W, const float* __restrict__ xv,
                 const float* __restrict__ bias, const float* __restrict__ resid,
                 float* __restrict__ out, int N) {
    int b = blockIdx.x;
    int w = threadIdx.x >> 6, lane = threadIdx.x & 63;
    int n = blockIdx.y*4 + w;
    __shared__ float xs[Hq];
    *(float4*)&xs[threadIdx.x*4] = *(const float4*)&xv[(size_t)b*Hq + threadIdx.x*4];
    __syncthreads();
    const float4* wr = (const float4*)(W + (size_t)n * Hq);
    float a = 0.f;
    #pragma unroll
    for (int c = 0; c < 4; ++c) {
        float4 wv = wr[c*64 + lane];
        float4 x4 = *(const float4*)&xs[c*256 + lane*4];
        a += wv.x*x4.x + wv.y*x4.y + wv.z*x4.z + wv.w*x4.w;
    }
    #pragma unroll
    for (int st = 32; st > 0; st >>= 1) a += __shfl_xor(a, st, 64);
    if (lane == 0) out[(size_t)b*N + n] = a + bias[n] + (resid ? resid[(size_t)b*Hq + n] : 0.f);
}

// ---------------- attention for the single last-position query ----------------
// 128 blocks x 1024 threads. Score: 16 lanes/row (coalesced uint4 + shfl-xor16).
// PV: 16-way S-split with packed b32 V loads, LDS combine.
__global__ __launch_bounds__(1024)
void attn_kernel(const unsigned short* __restrict__ KV,
                 const float* __restrict__ q, float* __restrict__ o) {
    int b = blockIdx.x >> 3, nh = blockIdx.x & 7;
    int tid = threadIdx.x;
    __shared__ float qs[DHq];
    __shared__ float p[Sq];
    __shared__ float redw[16];
    __shared__ float red2[16*DHq];
    if (tid < DHq) qs[tid] = q[b*Hq + nh*DHq + tid] * 0.08838834764831845f;  // fold 1/sqrt(128)
    __syncthreads();

    const int g = tid >> 4, l = tid & 15;
    const unsigned short* Kb = KV + (size_t)b*Sq*2048 + nh*DHq;
    float lmax = -1e30f;
    #pragma unroll 4
    for (int it = 0; it < 16; ++it) {
        int s = it*64 + g;
        union { uint4 v; unsigned short u[8]; } kk;
        kk.v = *(const uint4*)(Kb + (size_t)s*2048 + l*8);
        float a = 0.f;
        #pragma unroll
        for (int j = 0; j < 8; ++j) a += bf2f((unsigned int)kk.u[j]) * qs[l*8 + j];
        a += __shfl_xor(a, 1, 16);
        a += __shfl_xor(a, 2, 16);
        a += __shfl_xor(a, 4, 16);
        a += __shfl_xor(a, 8, 16);
        if (l == 0) p[s] = a;
        lmax = fmaxf(lmax, a);
    }
    #pragma unroll
    for (int st = 32; st > 0; st >>= 1) lmax = fmaxf(lmax, __shfl_xor(lmax, st, 64));
    if ((tid & 63) == 0) redw[tid >> 6] = lmax;
    __syncthreads();
    float mx = redw[0];
    #pragma unroll
    for (int i = 1; i < 16; ++i) mx = fmaxf(mx, redw[i]);

    float e = __expf(p[tid] - mx);
    float ls = e;
    #pragma unroll
    for (int st = 32; st > 0; st >>= 1) ls += __shfl_xor(ls, st, 64);
    __syncthreads();              // everyone done reading redw(max) and p(raw)
    p[tid] = e;
    if ((tid & 63) == 0) redw[tid >> 6] = ls;
    __syncthreads();
    float ssum = 0.f;
    #pragma unroll
    for (int i = 0; i < 16; ++i) ssum += redw[i];
    float inv = 1.f / ssum;

    // PV: thread -> (sb = s-block of 64, d2 = col pair)
    int d2 = (tid & 63) * 2, sb = tid >> 6;
    const unsigned short* Vb = KV + (size_t)b*Sq*2048 + 1024 + nh*DHq + d2;
    float a0 = 0.f, a1 = 0.f;
    for (int s = sb*64; s < sb*64 + 64; ++s) {
        unsigned int vv = *(const unsigned int*)(Vb + (size_t)s*2048);
        float pw = p[s];
        a0 += pw * bf2f(vv & 0xffffu);
        a1 += pw * bf2f(vv >> 16);
    }
    red2[sb*DHq + d2] = a0;
    red2[sb*DHq + d2 + 1] = a1;
    __syncthreads();
    if (tid < DHq) {
        float a = 0.f;
        #pragma unroll
        for (int i = 0; i < 16; ++i) a += red2[i*DHq + tid];
        o[b*Hq + nh*DHq + tid] = a * inv;
    }
}

extern "C" void kernel_launch(void* const* d_in, const int* in_sizes, int n_in,
                              void* d_out, int out_size, void* d_ws, size_t ws_size,
                              hipStream_t stream) {
    const float* x        = (const float*)d_in[0];
    const float* Wf       = (const float*)d_in[1];
    const float* bfv      = (const float*)d_in[2];
    const float* Wi       = (const float*)d_in[3];
    const float* biv      = (const float*)d_in[4];
    const float* Wh       = (const float*)d_in[5];
    const float* bhv      = (const float*)d_in[6];
    const float* in_proj_w= (const float*)d_in[7];
    const float* in_proj_b= (const float*)d_in[8];
    const float* out_w    = (const float*)d_in[9];
    const float* out_b    = (const float*)d_in[10];
    const float* fc_w     = (const float*)d_in[11];
    const float* fc_b     = (const float*)d_in[12];
    float* outp = (float*)d_out;

    // workspace carve (~196 MB)
    char* p = (char*)d_ws;
    auto alloc = [&](size_t bytes) -> void* {
        void* r = (void*)p; p += (bytes + 255) & ~(size_t)255; return r;
    };
    unsigned short* Wcat = (unsigned short*)alloc((size_t)Lq*3*HHq*2);  // 24 MB
    unsigned short* Wkv  = (unsigned short*)alloc((size_t)2048*Hq*2);   //  4 MB
    float*          Bias3= (float*)alloc((size_t)Lq*3*Hq*4);            // 48 KB
    unsigned short* actA = (unsigned short*)alloc((size_t)Mq*Hq*2);     // 32 MB
    unsigned short* actB = (unsigned short*)alloc((size_t)Mq*Hq*2);     // 32 MB
    unsigned short* Gpre = (unsigned short*)alloc((size_t)Mq*3*Hq*2);   // 96 MB
    float* Ps   = (float*)alloc((size_t)Bq*NCc*Hq*4);                   //  2 MB
    float* Asum = (float*)alloc((size_t)Bq*NCc*Hq*4);                   //  2 MB
    float* Hb   = (float*)alloc((size_t)Bq*NCc*Hq*4);                   //  2 MB
    unsigned short* KV = Gpre;                                          // alias (post-layers)
    float* xl   = (float*)alloc((size_t)Bq*Hq*4);
    float* qbuf = (float*)alloc((size_t)Bq*Hq*4);
    float* obuf = (float*)alloc((size_t)Bq*Hq*4);
    float* rbuf = (float*)alloc((size_t)Bq*Hq*4);

    // --- conversions ---
    cvt_kernel<<<Mq*Hq/256, 256, 0, stream>>>(x, actA, Mq*Hq);
    cvtW_kernel<<<Lq*3*HHq/256, 256, 0, stream>>>(Wf, Wi, Wh, Wcat);
    cvt_kernel<<<2048*Hq/256, 256, 0, stream>>>(in_proj_w + (size_t)Hq*Hq, Wkv, 2048*Hq);
    bias3_kernel<<<(Lq*3*Hq)/256, 256, 0, stream>>>(bfv, biv, bhv, Bias3);

    // --- minLSTM layers ---
    unsigned short* cur = actA;
    unsigned short* nxt = actB;
    for (int l = 0; l < Lq; ++l) {
        gemm_bt_kernel<<<dim3(3*Hq/128, Mq/128), 256, 0, stream>>>(
            cur, Wcat + (size_t)l*3*HHq, Bias3 + l*3*Hq, Gpre, 3*Hq, Hq);
        scan_sum_kernel<<<Bq*NCc*2, 256, 0, stream>>>(Gpre, Ps, Asum);
        scan_base_kernel<<<Bq*Hq/256, 256, 0, stream>>>(Ps, Asum, Hb);
        scan_out_kernel<<<Bq*NCc*2, 256, 0, stream>>>(Gpre, Hb, nxt);
        unsigned short* t = cur; cur = nxt; nxt = t;
    }

    // --- attention (only last-position query matters) ---
    gemm_bt_kernel<<<dim3(2048/128, Mq/128), 256, 0, stream>>>(
        cur, Wkv, in_proj_b + Hq, KV, 2048, Hq);
    xlast_kernel<<<Bq*Hq/256, 256, 0, stream>>>(cur, xl);
    gemv_kernel<<<dim3(Bq, Hq/4), 256, 0, stream>>>(in_proj_w, xl, in_proj_b, nullptr, qbuf, Hq);
    attn_kernel<<<Bq*NHq, 1024, 0, stream>>>(KV, qbuf, obuf);
    gemv_kernel<<<dim3(Bq, Hq/4), 256, 0, stream>>>(out_w, obuf, out_b, xl, rbuf, Hq);
    gemv_kernel<<<dim3(Bq, Oq/4), 256, 0, stream>>>(fc_w, rbuf, fc_b, nullptr, outp, Oq);
}

// Round 4
// 1064.508 us; speedup vs baseline: 1.9285x; 1.0966x over previous
//
#include <hip/hip_runtime.h>
#include <hip/hip_bf16.h>
#include <math.h>

// Problem constants (from reference setup_inputs)
#define Bq   16
#define Sq   1024
#define Hq   1024
#define Oq   256
#define Lq   4
#define NHq  8
#define DHq  128
#define Mq   (Bq*Sq)      // 16384 rows
#define HHq  (Hq*Hq)      // 1048576
#define NCc  32           // scan chunks
#define CTc  32           // timesteps per chunk

typedef __bf16 bf16x8 __attribute__((ext_vector_type(8)));
typedef float  f32x4  __attribute__((ext_vector_type(4)));

__device__ __forceinline__ float bf2f(unsigned int u) {
    union { unsigned int i; float f; } x; x.i = u << 16; return x.f;
}
__device__ __forceinline__ unsigned short f2bf(float f) {
    union { float f; unsigned int i; } x; x.f = f;
    unsigned int r = x.i + 0x7fffu + ((x.i >> 16) & 1u);   // RNE
    return (unsigned short)(r >> 16);
}
__device__ __forceinline__ float sigm(float x) { return 1.f / (1.f + __expf(-x)); }

// ---------------- fp32 -> bf16 convert ----------------
__global__ void cvt_kernel(const float* __restrict__ src, unsigned short* __restrict__ dst, int n) {
    int i = blockIdx.x * 256 + threadIdx.x;
    if (i < n) dst[i] = f2bf(src[i]);
}

// ---------------- fused weight convert: Wcat[l][f;i;h][H][H] ----------------
__global__ void cvtW_kernel(const float* __restrict__ Wf, const float* __restrict__ Wi,
                            const float* __restrict__ Wh, unsigned short* __restrict__ Wcat) {
    int i = blockIdx.x * 256 + threadIdx.x;     // L*3*HH
    int l = (i >> 20) / 3;
    int r = i - l * 3 * HHq;
    int g = r >> 20; int j = r & (HHq - 1);
    const float* s = (g == 0) ? Wf : (g == 1) ? Wi : Wh;
    Wcat[i] = f2bf(s[(size_t)l * HHq + j]);
}

// ---------------- assemble per-layer [bf;bi;bh] bias (L x 3072) ----------------
__global__ void bias3_kernel(const float* __restrict__ bf_, const float* __restrict__ bi_,
                             const float* __restrict__ bh_, float* __restrict__ out) {
    int i = blockIdx.x * 256 + threadIdx.x;          // L*3H = 12288
    int l = i / (3*Hq); int r = i % (3*Hq); int g = r >> 10; int j = r & (Hq-1);
    const float* s = (g == 0) ? bf_ : (g == 1) ? bi_ : bh_;
    out[i] = s[l*Hq + j];
}

// ---------------- bf16 GEMM: C[M,N] = A[M,K] * W[N,K]^T + bias (bf16 out) ----------------
// 128x128 tile, BK=64 (16 K-iters -> half the barrier drains of BK=32), 4 waves 2x2.
// global_load_lds width=16 staging; LDS [128][64] with octet XOR swizzle
// phys_chunk = c ^ (row&7): conflict-free ds_read_b128 fragments, and staging keeps
// the wave-uniform-base + lane*16 contiguity (lane l -> row rb+(l>>3), phys chunk l&7).
// Epilogue: direct scalar stores (R2 form; LDS-transpose variant measured SLOWER in R3).
__device__ __forceinline__ void gl2lds16(const unsigned short* g, unsigned short* l) {
    __builtin_amdgcn_global_load_lds((const __attribute__((address_space(1))) void*)g,
                                     (__attribute__((address_space(3))) void*)l, 16, 0, 0);
}

__global__ __launch_bounds__(256)
void gemm_bt_kernel(const unsigned short* __restrict__ A, const unsigned short* __restrict__ W,
                    const float* __restrict__ bias, unsigned short* __restrict__ C,
                    int N, int K)
{
    __shared__ unsigned short As[128*64];
    __shared__ unsigned short Ws[128*64];
    const int tid  = threadIdx.x;
    const int bn   = blockIdx.x, bm = blockIdx.y;
    const int wid  = tid >> 6, lane = tid & 63;
    const int wm   = (wid >> 1) * 64, wn = (wid & 1) * 64;
    const int l15  = lane & 15, quad = lane >> 4;

    const unsigned short* Ag = A + (size_t)(bm*128) * K;
    const unsigned short* Wg = W + (size_t)(bn*128) * K;

    // staging: wave w covers rows [w*32, w*32+32) in 4 issues of 8 rows each.
    // lane l -> row rb+q*8+(l>>3), phys chunk l&7 holding global chunk (l&7)^(l>>3).
    const int rl   = lane >> 3;
    const int cst  = (lane & 7) ^ rl;
    const int rb   = wid * 32;
    size_t goff[4];
    #pragma unroll
    for (int q = 0; q < 4; ++q)
        goff[q] = (size_t)(rb + q*8 + rl) * K + cst*8;
    unsigned short* lA = &As[rb*64];
    unsigned short* lW = &Ws[rb*64];

    const int key = l15 & 7;                 // fragment swizzle key (row&7 of tile row)

    f32x4 acc[4][4] = {};

    for (int k0 = 0; k0 < K; k0 += 64) {
        __syncthreads();                       // prior ds_reads done before overwrite
        #pragma unroll
        for (int q = 0; q < 4; ++q) {
            gl2lds16(Ag + goff[q] + k0, lA + q*512);
            gl2lds16(Wg + goff[q] + k0, lW + q*512);
        }
        __syncthreads();                       // vmcnt(0) drain + visibility
        #pragma unroll
        for (int ks = 0; ks < 2; ++ks) {
            bf16x8 af[4], wf[4];
            #pragma unroll
            for (int t = 0; t < 4; ++t) {
                int pc = ((ks*4 + quad) ^ key) * 8;
                af[t] = *(const bf16x8*)&As[(wm + t*16 + l15)*64 + pc];
                wf[t] = *(const bf16x8*)&Ws[(wn + t*16 + l15)*64 + pc];
            }
            #pragma unroll
            for (int tm = 0; tm < 4; ++tm)
                #pragma unroll
                for (int tn = 0; tn < 4; ++tn)
                    acc[tm][tn] = __builtin_amdgcn_mfma_f32_16x16x32_bf16(af[tm], wf[tn], acc[tm][tn], 0, 0, 0);
        }
    }

    // epilogue: C[row=quad*4+r][col=l15] per 16x16 tile (verified m89/m91 layout)
    #pragma unroll
    for (int tm = 0; tm < 4; ++tm) {
        int row0 = bm*128 + wm + tm*16 + quad*4;
        #pragma unroll
        for (int tn = 0; tn < 4; ++tn) {
            int col = bn*128 + wn + tn*16 + l15;
            float bv = bias[col];
            #pragma unroll
            for (int r = 0; r < 4; ++r)
                C[(size_t)(row0 + r) * N + col] = f2bf(acc[tm][tn][r] + bv);
        }
    }
}

// ---------------- fused gate + chunked scan ----------------
// Pass A: per (b,chunk,j-pair): P = prod fp, Aagg = local scan from h=0. 1024 blocks.
__global__ __launch_bounds__(256)
void scan_sum_kernel(const unsigned short* __restrict__ G,
                     float* __restrict__ Ps, float* __restrict__ Asum) {
    int bid = blockIdx.x;                    // B*NC*2 = 1024
    int tid = threadIdx.x;
    int b = bid >> 6; int r = bid & 63; int chunk = r >> 1; int jb = r & 1;
    int j = jb*512 + tid*2;
    size_t base = ((size_t)(b*Sq + chunk*CTc)) * 3072 + j;
    float P0 = 1.f, P1 = 1.f, A0 = 0.f, A1 = 0.f;
    for (int s = 0; s < CTc; ++s) {
        size_t ro = base + (size_t)s * 3072;
        unsigned int uf = *(const unsigned int*)(G + ro);
        unsigned int ui = *(const unsigned int*)(G + ro + 1024);
        unsigned int uh = *(const unsigned int*)(G + ro + 2048);
        float f0 = sigm(bf2f(uf & 0xffffu)), f1 = sigm(bf2f(uf >> 16));
        float i0 = sigm(bf2f(ui & 0xffffu)), i1 = sigm(bf2f(ui >> 16));
        float h0 = bf2f(uh & 0xffffu),       h1 = bf2f(uh >> 16);
        float rd0 = 1.f / (f0 + i0),         rd1 = 1.f / (f1 + i1);
        float fp0 = f0 * rd0,                fp1 = f1 * rd1;
        float ad0 = i0 * rd0 * h0,           ad1 = i1 * rd1 * h1;
        P0 *= fp0; A0 = fp0 * A0 + ad0;
        P1 *= fp1; A1 = fp1 * A1 + ad1;
    }
    int oi = (b*NCc + chunk)*Hq + j;
    Ps[oi] = P0; Ps[oi+1] = P1;
    Asum[oi] = A0; Asum[oi+1] = A1;
}

// Pass B: chunk-level prefix. h entering chunk c stored to Hb.
__global__ void scan_base_kernel(const float* __restrict__ Ps, const float* __restrict__ Asum,
                                 float* __restrict__ Hb) {
    int t = blockIdx.x * 256 + threadIdx.x;  // B*H = 16384
    int b = t >> 10, j = t & 1023;
    float h = 0.f;
    for (int c = 0; c < NCc; ++c) {
        int idx = (b*NCc + c)*Hq + j;
        Hb[idx] = h;
        h = Ps[idx] * h + Asum[idx];
    }
}

// Pass C: recompute gates, scan with correct init, write bf16 h.
__global__ __launch_bounds__(256)
void scan_out_kernel(const unsigned short* __restrict__ G, const float* __restrict__ Hb,
                     unsigned short* __restrict__ Ho) {
    int bid = blockIdx.x;                    // B*NC*2 = 1024
    int tid = threadIdx.x;
    int b = bid >> 6; int r = bid & 63; int chunk = r >> 1; int jb = r & 1;
    int j = jb*512 + tid*2;
    size_t base = ((size_t)(b*Sq + chunk*CTc)) * 3072 + j;
    int oi = (b*NCc + chunk)*Hq + j;
    float h0 = Hb[oi], h1 = Hb[oi+1];
    for (int s = 0; s < CTc; ++s) {
        size_t ro = base + (size_t)s * 3072;
        unsigned int uf = *(const unsigned int*)(G + ro);
        unsigned int ui = *(const unsigned int*)(G + ro + 1024);
        unsigned int uh = *(const unsigned int*)(G + ro + 2048);
        float f0 = sigm(bf2f(uf & 0xffffu)), f1 = sigm(bf2f(uf >> 16));
        float i0 = sigm(bf2f(ui & 0xffffu)), i1 = sigm(bf2f(ui >> 16));
        float g0 = bf2f(uh & 0xffffu),       g1 = bf2f(uh >> 16);
        float rd0 = 1.f / (f0 + i0),         rd1 = 1.f / (f1 + i1);
        h0 = f0 * rd0 * h0 + i0 * rd0 * g0;
        h1 = f1 * rd1 * h1 + i1 * rd1 * g1;
        unsigned int packed = (unsigned int)f2bf(h0) | ((unsigned int)f2bf(h1) << 16);
        *(unsigned int*)(Ho + (size_t)(b*Sq + chunk*CTc + s) * Hq + j) = packed;
    }
}

// ---------------- extract last-position activations as fp32 ----------------
__global__ void xlast_kernel(const unsigned short* __restrict__ act, float* __restrict__ xl) {
    int i = blockIdx.x * 256 + threadIdx.x;  // B*H
    int b = i >> 10, j = i & 1023;
    xl[i] = bf2f((unsigned int)act[((size_t)(b*Sq + Sq-1)) * Hq + j]);
}

// ---------------- wave-per-row GEMV: out[b,n] = W[n,:].x[b,:] + bias[n] (+resid[b,n]) ----------------
__global__ __launch_bounds__(256)
void gemv_kernel(const float* __restrict__ W, const float* __restrict__ xv,
                 const float* __restrict__ bias, const float* __restrict__ resid,
                 float* __restrict__ out, int N) {
    int b = blockIdx.x;
    int w = threadIdx.x >> 6, lane = threadIdx.x & 63;
    int n = blockIdx.y*4 + w;
    __shared__ float xs[Hq];
    *(float4*)&xs[threadIdx.x*4] = *(const float4*)&xv[(size_t)b*Hq + threadIdx.x*4];
    __syncthreads();
    const float4* wr = (const float4*)(W + (size_t)n * Hq);
    float a = 0.f;
    #pragma unroll
    for (int c = 0; c < 4; ++c) {
        float4 wv = wr[c*64 + lane];
        float4 x4 = *(const float4*)&xs[c*256 + lane*4];
        a += wv.x*x4.x + wv.y*x4.y + wv.z*x4.z + wv.w*x4.w;
    }
    #pragma unroll
    for (int st = 32; st > 0; st >>= 1) a += __shfl_xor(a, st, 64);
    if (lane == 0) out[(size_t)b*N + n] = a + bias[n] + (resid ? resid[(size_t)b*Hq + n] : 0.f);
}

// ---------------- attention for the single last-position query ----------------
// 128 blocks x 1024 threads. Score: 16 lanes/row (coalesced uint4 + shfl-xor16).
// PV: 16-way S-split with packed b32 V loads, LDS combine.
__global__ __launch_bounds__(1024)
void attn_kernel(const unsigned short* __restrict__ KV,
                 const float* __restrict__ q, float* __restrict__ o) {
    int b = blockIdx.x >> 3, nh = blockIdx.x & 7;
    int tid = threadIdx.x;
    __shared__ float qs[DHq];
    __shared__ float p[Sq];
    __shared__ float redw[16];
    __shared__ float red2[16*DHq];
    if (tid < DHq) qs[tid] = q[b*Hq + nh*DHq + tid] * 0.08838834764831845f;  // fold 1/sqrt(128)
    __syncthreads();

    const int g = tid >> 4, l = tid & 15;
    const unsigned short* Kb = KV + (size_t)b*Sq*2048 + nh*DHq;
    float lmax = -1e30f;
    #pragma unroll 4
    for (int it = 0; it < 16; ++it) {
        int s = it*64 + g;
        union { uint4 v; unsigned short u[8]; } kk;
        kk.v = *(const uint4*)(Kb + (size_t)s*2048 + l*8);
        float a = 0.f;
        #pragma unroll
        for (int j = 0; j < 8; ++j) a += bf2f((unsigned int)kk.u[j]) * qs[l*8 + j];
        a += __shfl_xor(a, 1, 16);
        a += __shfl_xor(a, 2, 16);
        a += __shfl_xor(a, 4, 16);
        a += __shfl_xor(a, 8, 16);
        if (l == 0) p[s] = a;
        lmax = fmaxf(lmax, a);
    }
    #pragma unroll
    for (int st = 32; st > 0; st >>= 1) lmax = fmaxf(lmax, __shfl_xor(lmax, st, 64));
    if ((tid & 63) == 0) redw[tid >> 6] = lmax;
    __syncthreads();
    float mx = redw[0];
    #pragma unroll
    for (int i = 1; i < 16; ++i) mx = fmaxf(mx, redw[i]);

    float e = __expf(p[tid] - mx);
    float ls = e;
    #pragma unroll
    for (int st = 32; st > 0; st >>= 1) ls += __shfl_xor(ls, st, 64);
    __syncthreads();              // everyone done reading redw(max) and p(raw)
    p[tid] = e;
    if ((tid & 63) == 0) redw[tid >> 6] = ls;
    __syncthreads();
    float ssum = 0.f;
    #pragma unroll
    for (int i = 0; i < 16; ++i) ssum += redw[i];
    float inv = 1.f / ssum;

    // PV: thread -> (sb = s-block of 64, d2 = col pair)
    int d2 = (tid & 63) * 2, sb = tid >> 6;
    const unsigned short* Vb = KV + (size_t)b*Sq*2048 + 1024 + nh*DHq + d2;
    float a0 = 0.f, a1 = 0.f;
    for (int s = sb*64; s < sb*64 + 64; ++s) {
        unsigned int vv = *(const unsigned int*)(Vb + (size_t)s*2048);
        float pw = p[s];
        a0 += pw * bf2f(vv & 0xffffu);
        a1 += pw * bf2f(vv >> 16);
    }
    red2[sb*DHq + d2] = a0;
    red2[sb*DHq + d2 + 1] = a1;
    __syncthreads();
    if (tid < DHq) {
        float a = 0.f;
        #pragma unroll
        for (int i = 0; i < 16; ++i) a += red2[i*DHq + tid];
        o[b*Hq + nh*DHq + tid] = a * inv;
    }
}

extern "C" void kernel_launch(void* const* d_in, const int* in_sizes, int n_in,
                              void* d_out, int out_size, void* d_ws, size_t ws_size,
                              hipStream_t stream) {
    const float* x        = (const float*)d_in[0];
    const float* Wf       = (const float*)d_in[1];
    const float* bfv      = (const float*)d_in[2];
    const float* Wi       = (const float*)d_in[3];
    const float* biv      = (const float*)d_in[4];
    const float* Wh       = (const float*)d_in[5];
    const float* bhv      = (const float*)d_in[6];
    const float* in_proj_w= (const float*)d_in[7];
    const float* in_proj_b= (const float*)d_in[8];
    const float* out_w    = (const float*)d_in[9];
    const float* out_b    = (const float*)d_in[10];
    const float* fc_w     = (const float*)d_in[11];
    const float* fc_b     = (const float*)d_in[12];
    float* outp = (float*)d_out;

    // workspace carve (~196 MB)
    char* p = (char*)d_ws;
    auto alloc = [&](size_t bytes) -> void* {
        void* r = (void*)p; p += (bytes + 255) & ~(size_t)255; return r;
    };
    unsigned short* Wcat = (unsigned short*)alloc((size_t)Lq*3*HHq*2);  // 24 MB
    unsigned short* Wkv  = (unsigned short*)alloc((size_t)2048*Hq*2);   //  4 MB
    float*          Bias3= (float*)alloc((size_t)Lq*3*Hq*4);            // 48 KB
    unsigned short* actA = (unsigned short*)alloc((size_t)Mq*Hq*2);     // 32 MB
    unsigned short* actB = (unsigned short*)alloc((size_t)Mq*Hq*2);     // 32 MB
    unsigned short* Gpre = (unsigned short*)alloc((size_t)Mq*3*Hq*2);   // 96 MB
    float* Ps   = (float*)alloc((size_t)Bq*NCc*Hq*4);                   //  2 MB
    float* Asum = (float*)alloc((size_t)Bq*NCc*Hq*4);                   //  2 MB
    float* Hb   = (float*)alloc((size_t)Bq*NCc*Hq*4);                   //  2 MB
    unsigned short* KV = Gpre;                                          // alias (post-layers)
    float* xl   = (float*)alloc((size_t)Bq*Hq*4);
    float* qbuf = (float*)alloc((size_t)Bq*Hq*4);
    float* obuf = (float*)alloc((size_t)Bq*Hq*4);
    float* rbuf = (float*)alloc((size_t)Bq*Hq*4);

    // --- conversions ---
    cvt_kernel<<<Mq*Hq/256, 256, 0, stream>>>(x, actA, Mq*Hq);
    cvtW_kernel<<<Lq*3*HHq/256, 256, 0, stream>>>(Wf, Wi, Wh, Wcat);
    cvt_kernel<<<2048*Hq/256, 256, 0, stream>>>(in_proj_w + (size_t)Hq*Hq, Wkv, 2048*Hq);
    bias3_kernel<<<(Lq*3*Hq)/256, 256, 0, stream>>>(bfv, biv, bhv, Bias3);

    // --- minLSTM layers ---
    unsigned short* cur = actA;
    unsigned short* nxt = actB;
    for (int l = 0; l < Lq; ++l) {
        gemm_bt_kernel<<<dim3(3*Hq/128, Mq/128), 256, 0, stream>>>(
            cur, Wcat + (size_t)l*3*HHq, Bias3 + l*3*Hq, Gpre, 3*Hq, Hq);
        scan_sum_kernel<<<Bq*NCc*2, 256, 0, stream>>>(Gpre, Ps, Asum);
        scan_base_kernel<<<Bq*Hq/256, 256, 0, stream>>>(Ps, Asum, Hb);
        scan_out_kernel<<<Bq*NCc*2, 256, 0, stream>>>(Gpre, Hb, nxt);
        unsigned short* t = cur; cur = nxt; nxt = t;
    }

    // --- attention (only last-position query matters) ---
    gemm_bt_kernel<<<dim3(2048/128, Mq/128), 256, 0, stream>>>(
        cur, Wkv, in_proj_b + Hq, KV, 2048, Hq);
    xlast_kernel<<<Bq*Hq/256, 256, 0, stream>>>(cur, xl);
    gemv_kernel<<<dim3(Bq, Hq/4), 256, 0, stream>>>(in_proj_w, xl, in_proj_b, nullptr, qbuf, Hq);
    attn_kernel<<<Bq*NHq, 1024, 0, stream>>>(KV, qbuf, obuf);
    gemv_kernel<<<dim3(Bq, Hq/4), 256, 0, stream>>>(out_w, obuf, out_b, xl, rbuf, Hq);
    gemv_kernel<<<dim3(Bq, Oq/4), 256, 0, stream>>>(fc_w, rbuf, fc_b, nullptr, outp, Oq);
}